// Round 7
// baseline (301.478 us; speedup 1.0000x reference)
//
#include <hip/hip_runtime.h>

typedef __attribute__((ext_vector_type(4))) float f32x4;
typedef __attribute__((ext_vector_type(8))) short bf16x8;
typedef unsigned short USHORT;

static __device__ __forceinline__ float bf2f(USHORT u) {
    return __uint_as_float(((unsigned)u) << 16);
}
static __device__ __forceinline__ USHORT f2bf(float f) {
    unsigned u = __float_as_uint(f);
    unsigned r = u + 0x7FFF + ((u >> 16) & 1);   // RTNE
    return (USHORT)(r >> 16);
}

// ---------------------------------------------------------------------------
// Zero d_out (fp32 retained accumulator target). 4096 blocks x 256 thr x 16 B.
// ---------------------------------------------------------------------------
__global__ __launch_bounds__(256) void k_zero(float* __restrict__ p) {
    const int i = (blockIdx.x * 256 + threadIdx.x) * 4;
    *(float4*)&p[i] = make_float4(0.f, 0.f, 0.f, 0.f);
}

// ---------------------------------------------------------------------------
// Weight transpose + cast: W fp32 [K=1024, N=1024] -> WT bf16 [N,K], 5 mats
// ---------------------------------------------------------------------------
struct TWArgs { const float* src[5]; USHORT* dst[5]; };

__global__ __launch_bounds__(256) void k_transpose_w(TWArgs ta) {
    const float* __restrict__ W  = ta.src[blockIdx.z];
    USHORT* __restrict__      WT = ta.dst[blockIdx.z];
    __shared__ USHORT t[64][65];
    const int k0 = blockIdx.y * 64, n0 = blockIdx.x * 64;
    const int tid = threadIdx.x;
#pragma unroll
    for (int s = 0; s < 4; s++) {
        int slot = tid + s * 256;
        int row = slot >> 4, c4 = (slot & 15) * 4;      // row = k, c4 = n
        float4 vv = *(const float4*)&W[(size_t)(k0 + row) * 1024 + n0 + c4];
        t[row][c4 + 0] = f2bf(vv.x);
        t[row][c4 + 1] = f2bf(vv.y);
        t[row][c4 + 2] = f2bf(vv.z);
        t[row][c4 + 3] = f2bf(vv.w);
    }
    __syncthreads();
#pragma unroll
    for (int s = 0; s < 2; s++) {
        int slot = tid + s * 256;
        int n = slot >> 3, c8 = (slot & 7) * 8;         // n = row of WT, c8 = k
        USHORT tmp[8];
#pragma unroll
        for (int u = 0; u < 8; u++) tmp[u] = t[c8 + u][n];
        *(int4*)&WT[(size_t)(n0 + n) * 1024 + k0 + c8] = *(int4*)tmp;
    }
}

// ---------------------------------------------------------------------------
// GEMM: C[M,1024] = act(A[M,1024] @ W + bias) * scale, W given as WT[N,K] bf16.
// A is fp32 (a_fp32=1, converted during staging) or bf16.
// 128x128 tile, BK=32, 256 threads (4 waves, 2x2), 16x16x32 bf16 MFMA.
// mode 0: bf16 row-major store; mode 1: sigmoid bf16 store; mode 2: V stored
// transposed as VT[b,h,d,s] PRE-SCALED by 0.99^{-(s mod 64)} (decay column
// factor folded in for the attention kernel); mode 3: fp32 store (final out).
// ---------------------------------------------------------------------------
struct GArgs {
    const void*   A;
    int           a_fp32;
    const USHORT* W[4];
    const float*  bias[4];
    void*         dst[4];
    USHORT*       dstv;       // VT output for mode 2
    float         scale[4];
    int           mode[4];
};

__global__ __launch_bounds__(256, 2) void k_gemm(GArgs ga) {
    const int z = blockIdx.z;
    const USHORT* __restrict__ BT = ga.W[z];
    __shared__ USHORT As[128 * 32];
    __shared__ USHORT Bs[128 * 32];
    const int tid = threadIdx.x;
    const int m0 = blockIdx.y * 128, n0 = blockIdx.x * 128;
    const int w = tid >> 6, l = tid & 63, lr = l & 15, q = l >> 4;
    const int wr = w >> 1, wc = w & 1;
    const int srow = tid >> 2, sco = (tid & 3) * 8;
    f32x4 acc[4][4] = {};
    for (int k0 = 0; k0 < 1024; k0 += 32) {
        USHORT a0[8], a1[8];
        if (ga.a_fp32) {
            const float* Af = (const float*)ga.A;
            float4 f0 = *(const float4*)&Af[(size_t)(m0 + srow) * 1024 + k0 + sco];
            float4 f1 = *(const float4*)&Af[(size_t)(m0 + srow) * 1024 + k0 + sco + 4];
            float4 f2 = *(const float4*)&Af[(size_t)(m0 + srow + 64) * 1024 + k0 + sco];
            float4 f3 = *(const float4*)&Af[(size_t)(m0 + srow + 64) * 1024 + k0 + sco + 4];
            a0[0]=f2bf(f0.x); a0[1]=f2bf(f0.y); a0[2]=f2bf(f0.z); a0[3]=f2bf(f0.w);
            a0[4]=f2bf(f1.x); a0[5]=f2bf(f1.y); a0[6]=f2bf(f1.z); a0[7]=f2bf(f1.w);
            a1[0]=f2bf(f2.x); a1[1]=f2bf(f2.y); a1[2]=f2bf(f2.z); a1[3]=f2bf(f2.w);
            a1[4]=f2bf(f3.x); a1[5]=f2bf(f3.y); a1[6]=f2bf(f3.z); a1[7]=f2bf(f3.w);
        } else {
            const USHORT* Ab = (const USHORT*)ga.A;
            *(int4*)a0 = *(const int4*)&Ab[(size_t)(m0 + srow) * 1024 + k0 + sco];
            *(int4*)a1 = *(const int4*)&Ab[(size_t)(m0 + srow + 64) * 1024 + k0 + sco];
        }
        int4 b0 = *(const int4*)&BT[(size_t)(n0 + srow) * 1024 + k0 + sco];
        int4 b1 = *(const int4*)&BT[(size_t)(n0 + srow + 64) * 1024 + k0 + sco];
        __syncthreads();
        *(int4*)&As[srow * 32 + sco] = *(int4*)a0;
        *(int4*)&As[(srow + 64) * 32 + sco] = *(int4*)a1;
        *(int4*)&Bs[srow * 32 + sco] = b0;
        *(int4*)&Bs[(srow + 64) * 32 + sco] = b1;
        __syncthreads();
        bf16x8 af[4], bfr[4];
#pragma unroll
        for (int mi = 0; mi < 4; mi++)
            af[mi] = *(const bf16x8*)&As[(wr * 64 + mi * 16 + lr) * 32 + q * 8];
#pragma unroll
        for (int ni = 0; ni < 4; ni++)
            bfr[ni] = *(const bf16x8*)&Bs[(wc * 64 + ni * 16 + lr) * 32 + q * 8];
#pragma unroll
        for (int mi = 0; mi < 4; mi++)
#pragma unroll
            for (int ni = 0; ni < 4; ni++)
                acc[mi][ni] = __builtin_amdgcn_mfma_f32_16x16x32_bf16(
                    af[mi], bfr[ni], acc[mi][ni], 0, 0, 0);
    }
    const float scale = ga.scale[z];
    const int mode = ga.mode[z];
    const float* __restrict__ bias = ga.bias[z];
#pragma unroll
    for (int ni = 0; ni < 4; ni++) {
        int col = n0 + wc * 64 + ni * 16 + lr;          // D col = lane&15 (B free)
        float bv = bias[col];
#pragma unroll
        for (int mi = 0; mi < 4; mi++) {
            int r0 = m0 + wr * 64 + mi * 16 + q * 4;    // D row = quad*4+reg (A free)
            float vr[4];
#pragma unroll
            for (int r = 0; r < 4; r++) {
                float v = acc[mi][ni][r] + bv;
                if (mode == 1) v = 1.0f / (1.0f + __expf(-v));
                vr[r] = v * scale;
            }
            if (mode == 3) {
                float* df = (float*)ga.dst[z];
#pragma unroll
                for (int r = 0; r < 4; r++)
                    df[(size_t)(r0 + r) * 1024 + col] = vr[r];
            } else if (mode == 2) {
                // V[b,s,h*64+d] -> VT[((b*16+h)*64+d)*2048 + s], 4 consecutive s
                // scaled by 0.99^{-(s & 63)} (column decay factor)
                int b = r0 >> 11, s = r0 & 2047;
                int h = col >> 6, d = col & 63;
                const float NP1 = 1.0101010101010102f;          // 0.99^-1
                float c0 = exp2f(0.014499569695115089f * (float)(s & 63));
                float c1 = c0 * NP1, c2 = c1 * NP1, c3 = c2 * NP1;
                *(ushort4*)&ga.dstv[(size_t)(((b * 16 + h) * 64) + d) * 2048 + s] =
                    make_ushort4(f2bf(vr[0] * c0), f2bf(vr[1] * c1),
                                 f2bf(vr[2] * c2), f2bf(vr[3] * c3));
            } else {
                USHORT* db = (USHORT*)ga.dst[z];
#pragma unroll
                for (int r = 0; r < 4; r++)
                    db[(size_t)(r0 + r) * 1024 + col] = f2bf(vr[r]);
            }
        }
    }
}

// ---------------------------------------------------------------------------
// Attention v2: balanced split + padded LDS + folded decay.
// Block = (bh, p, h): processes i-blocks iblk=p then 15-p; j-tiles for half h
// (h=0: tiles 0..iblk, h=1: tiles iblk+1..2iblk+1) -> every block does exactly
// 17 j-tile iterations. LDS row stride 72 (144 B) kills b128 bank conflicts.
// Column decay pre-folded into VT; row decay = one exp2f per wave-tile.
// P packed to bf16 by truncation (v_perm); uniform scale bias cancels in LN.
// Partial retained accumulated into fp32 R via atomicAdd (R pre-zeroed).
// ---------------------------------------------------------------------------
__global__ __launch_bounds__(256, 2) void k_attn(const USHORT* __restrict__ Q,
                                                 const USHORT* __restrict__ K,
                                                 const USHORT* __restrict__ VT,
                                                 float* __restrict__ R) {
    const int bh = blockIdx.x;
    const int b = bh >> 4, h = bh & 15;
    const int p = blockIdx.y;        // 0..7
    const int hh = blockIdx.z;       // 0..1
    const int tid = threadIdx.x, w = tid >> 6, l = tid & 63, lr = l & 15, q = l >> 4;
    __shared__ USHORT Qs[128 * 72];
    __shared__ USHORT Ks[64 * 72];
    __shared__ USHORT Vs[64 * 72];
    __shared__ USHORT Ps[4][32 * 72];
    const float L2D = -0.014499569695115089f;   // log2(0.99)
    const float C16 = 0.8514577710948755f;      // 0.99^16
#pragma unroll
    for (int phase = 0; phase < 2; phase++) {
        const int iblk = phase ? (15 - p) : p;
        const int i0 = iblk * 128;
        const int iw0 = i0 + w * 32;
        __syncthreads();   // protect LDS reuse across phases
        // stage Q tile [128 i][64 d] -> padded
#pragma unroll
        for (int s = 0; s < 4; s++) {
            int slot = tid + s * 256;
            int rw = slot >> 3, c8 = (slot & 7) * 8;
            *(int4*)&Qs[rw * 72 + c8] =
                *(const int4*)&Q[(size_t)(b * 2048 + i0 + rw) * 1024 + h * 64 + c8];
        }
        const int jstart = hh ? (iblk + 1) : 0;
        const int count = iblk + 1;
        f32x4 accr[4][2] = {};
        for (int jb = 0; jb < count; jb++) {
            const int j0 = (jstart + jb) * 64;
            {   // stage K tile [64j x 64d] and VT tile [64d x 64j] (pre-scaled)
                int r0_ = tid >> 3, c0 = (tid & 7) * 8;
                int slot1 = tid + 256;
                int r1_ = slot1 >> 3, c1 = (slot1 & 7) * 8;
                int4 kv0 = *(const int4*)&K[(size_t)(b * 2048 + j0 + r0_) * 1024 + h * 64 + c0];
                int4 kv1 = *(const int4*)&K[(size_t)(b * 2048 + j0 + r1_) * 1024 + h * 64 + c1];
                int4 vv0 = *(const int4*)&VT[(size_t)(bh * 64 + r0_) * 2048 + j0 + c0];
                int4 vv1 = *(const int4*)&VT[(size_t)(bh * 64 + r1_) * 2048 + j0 + c1];
                __syncthreads();
                *(int4*)&Ks[r0_ * 72 + c0] = kv0;
                *(int4*)&Ks[r1_ * 72 + c1] = kv1;
                *(int4*)&Vs[r0_ * 72 + c0] = vv0;
                *(int4*)&Vs[r1_ * 72 + c1] = vv1;
                __syncthreads();
            }
            if (j0 <= iw0 + 31) {
                // Pt[64j x 32i] = K Q^T : D row=j (quad*4+reg), col=i (lane&15)
                f32x4 accp[4][2] = {};
#pragma unroll
                for (int kk = 0; kk < 2; kk++) {
                    bf16x8 bqf[2];
#pragma unroll
                    for (int it = 0; it < 2; it++)
                        bqf[it] = *(const bf16x8*)&Qs[(w * 32 + it * 16 + lr) * 72 + kk * 32 + q * 8];
#pragma unroll
                    for (int jt = 0; jt < 4; jt++) {
                        bf16x8 akf = *(const bf16x8*)&Ks[(jt * 16 + lr) * 72 + kk * 32 + q * 8];
#pragma unroll
                        for (int it = 0; it < 2; it++)
                            accp[jt][it] = __builtin_amdgcn_mfma_f32_16x16x32_bf16(
                                akf, bqf[it], accp[jt][it], 0, 0, 0);
                    }
                }
                // row decay: one exp2f per tile; column decay already in Vs.
                const float fb = exp2f(L2D * (float)(iw0 - j0 + lr));
                const float F[2] = { fb, fb * C16 };
                const bool partial = (j0 + 63 > iw0);
#pragma unroll
                for (int jt = 0; jt < 4; jt++) {
#pragma unroll
                    for (int it = 0; it < 2; it++) {
                        float v0 = accp[jt][it][0] * F[it];
                        float v1 = accp[jt][it][1] * F[it];
                        float v2 = accp[jt][it][2] * F[it];
                        float v3 = accp[jt][it][3] * F[it];
                        if (partial) {
                            const int ii = iw0 + it * 16 + lr;
                            const int jj = j0 + jt * 16 + q * 4;
                            if (jj + 0 > ii) v0 = 0.0f;
                            if (jj + 1 > ii) v1 = 0.0f;
                            if (jj + 2 > ii) v2 = 0.0f;
                            if (jj + 3 > ii) v3 = 0.0f;
                        }
                        // truncation-pack hi16 pairs (systematic bias cancels in LN)
                        unsigned w0 = __builtin_amdgcn_perm(
                            __float_as_uint(v1), __float_as_uint(v0), 0x07060302u);
                        unsigned w1 = __builtin_amdgcn_perm(
                            __float_as_uint(v3), __float_as_uint(v2), 0x07060302u);
                        *(uint2*)&Ps[w][(it * 16 + lr) * 72 + jt * 16 + q * 4] =
                            make_uint2(w0, w1);
                    }
                }
                // within-wave LDS RAW fence (Ps write -> Ps read)
                asm volatile("s_waitcnt lgkmcnt(0)" ::: "memory");
                // retained^T[64d x 32i] += Vs * Pt
#pragma unroll
                for (int kk = 0; kk < 2; kk++) {
                    bf16x8 bpf[2];
#pragma unroll
                    for (int it = 0; it < 2; it++)
                        bpf[it] = *(const bf16x8*)&Ps[w][(it * 16 + lr) * 72 + kk * 32 + q * 8];
#pragma unroll
                    for (int dt = 0; dt < 4; dt++) {
                        bf16x8 avf = *(const bf16x8*)&Vs[(dt * 16 + lr) * 72 + kk * 32 + q * 8];
#pragma unroll
                        for (int it = 0; it < 2; it++)
                            accr[dt][it] = __builtin_amdgcn_mfma_f32_16x16x32_bf16(
                                avf, bpf[it], accr[dt][it], 0, 0, 0);
                    }
                }
            }
        }
        // accumulate partial retained into fp32 R
#pragma unroll
        for (int it = 0; it < 2; it++) {
            int i = i0 + w * 32 + it * 16 + lr;
#pragma unroll
            for (int dt = 0; dt < 4; dt++) {
                size_t base = (size_t)(b * 2048 + i) * 1024 + h * 64 + dt * 16 + q * 4;
#pragma unroll
                for (int r = 0; r < 4; r++)
                    atomicAdd(&R[base + r], accr[dt][it][r]);
            }
        }
    }
}

// ---------------------------------------------------------------------------
// LayerNorm over D=1024 (R fp32) + gate multiply. One block per row.
// ---------------------------------------------------------------------------
__global__ __launch_bounds__(256) void k_ln_gate(const float* __restrict__ R,
                                                 const USHORT* __restrict__ G,
                                                 const float* __restrict__ gamma,
                                                 const float* __restrict__ beta,
                                                 USHORT* __restrict__ NG) {
    const int row = blockIdx.x, tid = threadIdx.x;
    const float4 v = *(const float4*)&R[(size_t)row * 1024 + tid * 4];
    float vv[4] = { v.x, v.y, v.z, v.w };
    float s  = vv[0] + vv[1] + vv[2] + vv[3];
    float s2 = vv[0]*vv[0] + vv[1]*vv[1] + vv[2]*vv[2] + vv[3]*vv[3];
#pragma unroll
    for (int o = 32; o > 0; o >>= 1) {
        s  += __shfl_down(s, o, 64);
        s2 += __shfl_down(s2, o, 64);
    }
    __shared__ float red[8];
    if ((tid & 63) == 0) { red[tid >> 6] = s; red[4 + (tid >> 6)] = s2; }
    __syncthreads();
    const float ts  = red[0] + red[1] + red[2] + red[3];
    const float ts2 = red[4] + red[5] + red[6] + red[7];
    const float mu  = ts * (1.0f / 1024.0f);
    const float var = ts2 * (1.0f / 1024.0f) - mu * mu;
    const float inv = rsqrtf(var + 1e-5f);
    ushort4 g4 = *(const ushort4*)&G[(size_t)row * 1024 + tid * 4];
    float4 gm = *(const float4*)&gamma[tid * 4];
    float4 bt = *(const float4*)&beta[tid * 4];
    USHORT gg[4]  = { g4.x, g4.y, g4.z, g4.w };
    float  gmm[4] = { gm.x, gm.y, gm.z, gm.w };
    float  btt[4] = { bt.x, bt.y, bt.z, bt.w };
    USHORT o4[4];
#pragma unroll
    for (int u = 0; u < 4; u++) {
        float nv = (vv[u] - mu) * inv * gmm[u] + btt[u];
        o4[u] = f2bf(nv * bf2f(gg[u]));
    }
    *(ushort4*)&NG[(size_t)row * 1024 + tid * 4] = make_ushort4(o4[0], o4[1], o4[2], o4[3]);
}

// ---------------------------------------------------------------------------
extern "C" void kernel_launch(void* const* d_in, const int* in_sizes, int n_in,
                              void* d_out, int out_size, void* d_ws, size_t ws_size,
                              hipStream_t stream) {
    const float* x     = (const float*)d_in[0];
    const float* Wq    = (const float*)d_in[1];
    const float* bq    = (const float*)d_in[2];
    const float* Wk    = (const float*)d_in[3];
    const float* bk    = (const float*)d_in[4];
    const float* Wv    = (const float*)d_in[5];
    const float* bv    = (const float*)d_in[6];
    const float* Wg    = (const float*)d_in[7];
    const float* bg    = (const float*)d_in[8];
    const float* Wo    = (const float*)d_in[9];
    const float* bo    = (const float*)d_in[10];
    const float* gamma = (const float*)d_in[11];
    const float* beta  = (const float*)d_in[12];

    // Workspace: 42 MB.
    char* ws = (char*)d_ws;
    const size_t MB = 1 << 20;
    USHORT* WqT = (USHORT*)(ws + 0 * MB);
    USHORT* WkT = (USHORT*)(ws + 2 * MB);
    USHORT* WvT = (USHORT*)(ws + 4 * MB);
    USHORT* WgT = (USHORT*)(ws + 6 * MB);
    USHORT* WoT = (USHORT*)(ws + 8 * MB);
    USHORT* Qb  = (USHORT*)(ws + 10 * MB);
    USHORT* Kb  = (USHORT*)(ws + 18 * MB);
    USHORT* VTb = (USHORT*)(ws + 26 * MB);
    USHORT* Gb  = (USHORT*)(ws + 34 * MB);
    USHORT* NGb = Qb;                 // Qb dead after attention
    float*  Rf  = (float*)d_out;      // fp32 retained accumulator in d_out (16 MB);
                                      // fully overwritten by the final fp32 GEMM

    k_zero<<<4096, 256, 0, stream>>>(Rf);
    {   // transpose+cast all 5 weights to bf16 [N,K]
        TWArgs ta;
        ta.src[0] = Wq; ta.src[1] = Wk; ta.src[2] = Wv; ta.src[3] = Wg; ta.src[4] = Wo;
        ta.dst[0] = WqT; ta.dst[1] = WkT; ta.dst[2] = WvT; ta.dst[3] = WgT; ta.dst[4] = WoT;
        k_transpose_w<<<dim3(16, 16, 5), 256, 0, stream>>>(ta);
    }
    {   // 4 fused projections from fp32 x: Q (scaled 1/8), K, V (transposed+scaled), G (sigmoid)
        GArgs ga;
        ga.A = (const void*)x; ga.a_fp32 = 1;
        ga.W[0] = WqT; ga.W[1] = WkT; ga.W[2] = WvT; ga.W[3] = WgT;
        ga.bias[0] = bq; ga.bias[1] = bk; ga.bias[2] = bv; ga.bias[3] = bg;
        ga.dst[0] = Qb; ga.dst[1] = Kb; ga.dst[2] = nullptr; ga.dst[3] = Gb;
        ga.dstv = VTb;
        ga.scale[0] = 0.125f; ga.scale[1] = 1.0f; ga.scale[2] = 1.0f; ga.scale[3] = 1.0f;
        ga.mode[0] = 0; ga.mode[1] = 0; ga.mode[2] = 2; ga.mode[3] = 1;
        k_gemm<<<dim3(8, 32, 4), 256, 0, stream>>>(ga);
    }
    k_attn<<<dim3(32, 8, 2), 256, 0, stream>>>(Qb, Kb, VTb, Rf);
    k_ln_gate<<<4096, 256, 0, stream>>>(Rf, Gb, gamma, beta, NGb);
    {   // output projection -> d_out as FP32 (mode 3), overwrites Rf
        GArgs go;
        go.A = (const void*)NGb; go.a_fp32 = 0;
        for (int i = 0; i < 4; i++) {
            go.W[i] = WoT; go.bias[i] = bo; go.dst[i] = d_out;
            go.scale[i] = 1.0f; go.mode[i] = 3;
        }
        go.dstv = nullptr;
        k_gemm<<<dim3(8, 32, 1), 256, 0, stream>>>(go);
    }
}

// Round 8
// 233.609 us; speedup vs baseline: 1.2905x; 1.2905x over previous
//
#include <hip/hip_runtime.h>

typedef __attribute__((ext_vector_type(4))) float f32x4;
typedef __attribute__((ext_vector_type(8))) short bf16x8;
typedef unsigned short USHORT;

static __device__ __forceinline__ float bf2f(USHORT u) {
    return __uint_as_float(((unsigned)u) << 16);
}
static __device__ __forceinline__ USHORT f2bf(float f) {
    unsigned u = __float_as_uint(f);
    unsigned r = u + 0x7FFF + ((u >> 16) & 1);   // RTNE
    return (USHORT)(r >> 16);
}

// 16B/lane async global->LDS (m97 recipe). LDS dst must be wave-uniform base
// + lane*16 — our staging layouts satisfy this (LDS byte addr == tid*16).
#define GLDS16(gp, lp) __builtin_amdgcn_global_load_lds(                      \
    (const __attribute__((address_space(1))) unsigned int*)(gp),              \
    (__attribute__((address_space(3))) unsigned int*)(lp), 16, 0, 0)

// ---------------------------------------------------------------------------
// Cast x fp32 [4096,1024] -> bf16 (into d_out scratch; dead before attn).
// ---------------------------------------------------------------------------
__global__ __launch_bounds__(256) void k_cast_x(const float* __restrict__ x,
                                                USHORT* __restrict__ xb) {
    const int i = (blockIdx.x * 256 + threadIdx.x) * 4;
    float4 v = *(const float4*)&x[i];
    *(ushort4*)&xb[i] = make_ushort4(f2bf(v.x), f2bf(v.y), f2bf(v.z), f2bf(v.w));
}

// ---------------------------------------------------------------------------
// Weight transpose + cast: W fp32 [K=1024, N=1024] -> WT bf16 [N,K], 5 mats
// ---------------------------------------------------------------------------
struct TWArgs { const float* src[5]; USHORT* dst[5]; };

__global__ __launch_bounds__(256) void k_transpose_w(TWArgs ta) {
    const float* __restrict__ W  = ta.src[blockIdx.z];
    USHORT* __restrict__      WT = ta.dst[blockIdx.z];
    __shared__ USHORT t[64][65];
    const int k0 = blockIdx.y * 64, n0 = blockIdx.x * 64;
    const int tid = threadIdx.x;
#pragma unroll
    for (int s = 0; s < 4; s++) {
        int slot = tid + s * 256;
        int row = slot >> 4, c4 = (slot & 15) * 4;      // row = k, c4 = n
        float4 vv = *(const float4*)&W[(size_t)(k0 + row) * 1024 + n0 + c4];
        t[row][c4 + 0] = f2bf(vv.x);
        t[row][c4 + 1] = f2bf(vv.y);
        t[row][c4 + 2] = f2bf(vv.z);
        t[row][c4 + 3] = f2bf(vv.w);
    }
    __syncthreads();
#pragma unroll
    for (int s = 0; s < 2; s++) {
        int slot = tid + s * 256;
        int n = slot >> 3, c8 = (slot & 7) * 8;         // n = row of WT, c8 = k
        USHORT tmp[8];
#pragma unroll
        for (int u = 0; u < 8; u++) tmp[u] = t[c8 + u][n];
        *(int4*)&WT[(size_t)(n0 + n) * 1024 + k0 + c8] = *(int4*)tmp;
    }
}

// ---------------------------------------------------------------------------
// GEMM: C[M,1024] = act(A[M,1024] @ W + bias) * scale, A bf16, W = WT[N,K] bf16.
// 128x128 tile, BK=32, 256 threads (4 waves, 2x2), 16x16x32 bf16 MFMA.
// Staging via global_load_lds width=16 (m97). LDS dst addr = tid*16 bytes.
// mode 0: bf16 store; mode 1: sigmoid bf16; mode 2: V transposed+decay-scaled
// as VT[b,h,d,s]; mode 3: fp32 store (final output).
// ---------------------------------------------------------------------------
struct GArgs {
    const USHORT* A;
    const USHORT* W[4];
    const float*  bias[4];
    void*         dst[4];
    USHORT*       dstv;       // VT output for mode 2
    float         scale[4];
    int           mode[4];
};

__global__ __launch_bounds__(256, 2) void k_gemm(GArgs ga) {
    const int z = blockIdx.z;
    const USHORT* __restrict__ A  = ga.A;
    const USHORT* __restrict__ BT = ga.W[z];
    __shared__ USHORT As[128 * 32];
    __shared__ USHORT Bs[128 * 32];
    const int tid = threadIdx.x;
    const int m0 = blockIdx.y * 128, n0 = blockIdx.x * 128;
    const int w = tid >> 6, l = tid & 63, lr = l & 15, q = l >> 4;
    const int wr = w >> 1, wc = w & 1;
    const int srow = tid >> 2, sco = (tid & 3) * 8;     // LDS byte addr = tid*16
    f32x4 acc[4][4] = {};
    for (int k0 = 0; k0 < 1024; k0 += 32) {
        __syncthreads();
        GLDS16(&A [(size_t)(m0 + srow)      * 1024 + k0 + sco], &As[srow * 32 + sco]);
        GLDS16(&A [(size_t)(m0 + srow + 64) * 1024 + k0 + sco], &As[(srow + 64) * 32 + sco]);
        GLDS16(&BT[(size_t)(n0 + srow)      * 1024 + k0 + sco], &Bs[srow * 32 + sco]);
        GLDS16(&BT[(size_t)(n0 + srow + 64) * 1024 + k0 + sco], &Bs[(srow + 64) * 32 + sco]);
        __syncthreads();
        bf16x8 af[4], bfr[4];
#pragma unroll
        for (int mi = 0; mi < 4; mi++)
            af[mi] = *(const bf16x8*)&As[(wr * 64 + mi * 16 + lr) * 32 + q * 8];
#pragma unroll
        for (int ni = 0; ni < 4; ni++)
            bfr[ni] = *(const bf16x8*)&Bs[(wc * 64 + ni * 16 + lr) * 32 + q * 8];
#pragma unroll
        for (int mi = 0; mi < 4; mi++)
#pragma unroll
            for (int ni = 0; ni < 4; ni++)
                acc[mi][ni] = __builtin_amdgcn_mfma_f32_16x16x32_bf16(
                    af[mi], bfr[ni], acc[mi][ni], 0, 0, 0);
    }
    const float scale = ga.scale[z];
    const int mode = ga.mode[z];
    const float* __restrict__ bias = ga.bias[z];
#pragma unroll
    for (int ni = 0; ni < 4; ni++) {
        int col = n0 + wc * 64 + ni * 16 + lr;          // D col = lane&15 (B free)
        float bv = bias[col];
#pragma unroll
        for (int mi = 0; mi < 4; mi++) {
            int r0 = m0 + wr * 64 + mi * 16 + q * 4;    // D row = quad*4+reg (A free)
            float vr[4];
#pragma unroll
            for (int r = 0; r < 4; r++) {
                float v = acc[mi][ni][r] + bv;
                if (mode == 1) v = 1.0f / (1.0f + __expf(-v));
                vr[r] = v * scale;
            }
            if (mode == 3) {
                float* df = (float*)ga.dst[z];
#pragma unroll
                for (int r = 0; r < 4; r++)
                    df[(size_t)(r0 + r) * 1024 + col] = vr[r];
            } else if (mode == 2) {
                // V[b,s,h*64+d] -> VT[((b*16+h)*64+d)*2048 + s], 4 consecutive s
                // scaled by 0.99^{-(s & 63)} (column decay factor)
                int b = r0 >> 11, s = r0 & 2047;
                int h = col >> 6, d = col & 63;
                const float NP1 = 1.0101010101010102f;          // 0.99^-1
                float c0 = exp2f(0.014499569695115089f * (float)(s & 63));
                float c1 = c0 * NP1, c2 = c1 * NP1, c3 = c2 * NP1;
                *(ushort4*)&ga.dstv[(size_t)(((b * 16 + h) * 64) + d) * 2048 + s] =
                    make_ushort4(f2bf(vr[0] * c0), f2bf(vr[1] * c1),
                                 f2bf(vr[2] * c2), f2bf(vr[3] * c3));
            } else {
                USHORT* db = (USHORT*)ga.dst[z];
#pragma unroll
                for (int r = 0; r < 4; r++)
                    db[(size_t)(r0 + r) * 1024 + col] = f2bf(vr[r]);
            }
        }
    }
}

// ---------------------------------------------------------------------------
// Attention v3: single writer per i-block (no atomics) + balanced pairing +
// padded LDS (stride 72) + folded decay + v_perm P-packing.
// iblk = rr<8 ? rr : 23-rr  => co-resident pairs sum to constant work.
// Retained written fp32 straight to R (=d_out).
// ---------------------------------------------------------------------------
__global__ __launch_bounds__(256, 2) void k_attn(const USHORT* __restrict__ Q,
                                                 const USHORT* __restrict__ K,
                                                 const USHORT* __restrict__ VT,
                                                 float* __restrict__ R) {
    const int bh = blockIdx.x;
    const int b = bh >> 4, h = bh & 15;
    const int rr = blockIdx.y;
    const int iblk = (rr < 8) ? rr : 23 - rr;
    const int i0 = iblk * 128;
    const int tid = threadIdx.x, w = tid >> 6, l = tid & 63, lr = l & 15, q = l >> 4;
    __shared__ USHORT Qs[128 * 72];
    __shared__ USHORT Ks[64 * 72];
    __shared__ USHORT Vs[64 * 72];
    __shared__ USHORT Ps[4][32 * 72];
    const float L2D = -0.014499569695115089f;   // log2(0.99)
    const float C16 = 0.8514577710948755f;      // 0.99^16
    // stage Q tile [128 i][64 d] -> padded
#pragma unroll
    for (int s = 0; s < 4; s++) {
        int slot = tid + s * 256;
        int rw = slot >> 3, c8 = (slot & 7) * 8;
        *(int4*)&Qs[rw * 72 + c8] =
            *(const int4*)&Q[(size_t)(b * 2048 + i0 + rw) * 1024 + h * 64 + c8];
    }
    const int iw0 = i0 + w * 32;
    f32x4 accr[4][2] = {};
    const int njb = 2 * iblk + 2;
    for (int jb = 0; jb < njb; jb++) {
        const int j0 = jb * 64;
        {   // stage K tile [64j x 64d] and VT tile [64d x 64j] (pre-scaled)
            int r0_ = tid >> 3, c0 = (tid & 7) * 8;
            int slot1 = tid + 256;
            int r1_ = slot1 >> 3, c1 = (slot1 & 7) * 8;
            int4 kv0 = *(const int4*)&K[(size_t)(b * 2048 + j0 + r0_) * 1024 + h * 64 + c0];
            int4 kv1 = *(const int4*)&K[(size_t)(b * 2048 + j0 + r1_) * 1024 + h * 64 + c1];
            int4 vv0 = *(const int4*)&VT[(size_t)(bh * 64 + r0_) * 2048 + j0 + c0];
            int4 vv1 = *(const int4*)&VT[(size_t)(bh * 64 + r1_) * 2048 + j0 + c1];
            __syncthreads();
            *(int4*)&Ks[r0_ * 72 + c0] = kv0;
            *(int4*)&Ks[r1_ * 72 + c1] = kv1;
            *(int4*)&Vs[r0_ * 72 + c0] = vv0;
            *(int4*)&Vs[r1_ * 72 + c1] = vv1;
            __syncthreads();
        }
        if (j0 <= iw0 + 31) {
            // Pt[64j x 32i] = K Q^T : D row=j (quad*4+reg), col=i (lane&15)
            f32x4 accp[4][2] = {};
#pragma unroll
            for (int kk = 0; kk < 2; kk++) {
                bf16x8 bqf[2];
#pragma unroll
                for (int it = 0; it < 2; it++)
                    bqf[it] = *(const bf16x8*)&Qs[(w * 32 + it * 16 + lr) * 72 + kk * 32 + q * 8];
#pragma unroll
                for (int jt = 0; jt < 4; jt++) {
                    bf16x8 akf = *(const bf16x8*)&Ks[(jt * 16 + lr) * 72 + kk * 32 + q * 8];
#pragma unroll
                    for (int it = 0; it < 2; it++)
                        accp[jt][it] = __builtin_amdgcn_mfma_f32_16x16x32_bf16(
                            akf, bqf[it], accp[jt][it], 0, 0, 0);
                }
            }
            // row decay: one exp2f per tile; column decay already in Vs.
            const float fb = exp2f(L2D * (float)(iw0 - j0 + lr));
            const float F[2] = { fb, fb * C16 };
            const bool partial = (j0 + 63 > iw0);
#pragma unroll
            for (int jt = 0; jt < 4; jt++) {
#pragma unroll
                for (int it = 0; it < 2; it++) {
                    float v0 = accp[jt][it][0] * F[it];
                    float v1 = accp[jt][it][1] * F[it];
                    float v2 = accp[jt][it][2] * F[it];
                    float v3 = accp[jt][it][3] * F[it];
                    if (partial) {
                        const int ii = iw0 + it * 16 + lr;
                        const int jj = j0 + jt * 16 + q * 4;
                        if (jj + 0 > ii) v0 = 0.0f;
                        if (jj + 1 > ii) v1 = 0.0f;
                        if (jj + 2 > ii) v2 = 0.0f;
                        if (jj + 3 > ii) v3 = 0.0f;
                    }
                    // truncation-pack hi16 pairs (uniform scale bias cancels in LN)
                    unsigned w0 = __builtin_amdgcn_perm(
                        __float_as_uint(v1), __float_as_uint(v0), 0x07060302u);
                    unsigned w1 = __builtin_amdgcn_perm(
                        __float_as_uint(v3), __float_as_uint(v2), 0x07060302u);
                    *(uint2*)&Ps[w][(it * 16 + lr) * 72 + jt * 16 + q * 4] =
                        make_uint2(w0, w1);
                }
            }
            // within-wave LDS RAW fence (Ps write -> Ps read)
            asm volatile("s_waitcnt lgkmcnt(0)" ::: "memory");
            // retained^T[64d x 32i] += Vs * Pt
#pragma unroll
            for (int kk = 0; kk < 2; kk++) {
                bf16x8 bpf[2];
#pragma unroll
                for (int it = 0; it < 2; it++)
                    bpf[it] = *(const bf16x8*)&Ps[w][(it * 16 + lr) * 72 + kk * 32 + q * 8];
#pragma unroll
                for (int dt = 0; dt < 4; dt++) {
                    bf16x8 avf = *(const bf16x8*)&Vs[(dt * 16 + lr) * 72 + kk * 32 + q * 8];
#pragma unroll
                    for (int it = 0; it < 2; it++)
                        accr[dt][it] = __builtin_amdgcn_mfma_f32_16x16x32_bf16(
                            avf, bpf[it], accr[dt][it], 0, 0, 0);
                }
            }
        }
    }
    // plain fp32 stores: lane's 4 regs = 4 consecutive d -> float4
#pragma unroll
    for (int it = 0; it < 2; it++) {
        int i = i0 + w * 32 + it * 16 + lr;
#pragma unroll
        for (int dt = 0; dt < 4; dt++) {
            *(f32x4*)&R[(size_t)(b * 2048 + i) * 1024 + h * 64 + dt * 16 + q * 4] =
                accr[dt][it];
        }
    }
}

// ---------------------------------------------------------------------------
// LayerNorm over D=1024 (R fp32) + gate multiply. One block per row.
// ---------------------------------------------------------------------------
__global__ __launch_bounds__(256) void k_ln_gate(const float* __restrict__ R,
                                                 const USHORT* __restrict__ G,
                                                 const float* __restrict__ gamma,
                                                 const float* __restrict__ beta,
                                                 USHORT* __restrict__ NG) {
    const int row = blockIdx.x, tid = threadIdx.x;
    const float4 v = *(const float4*)&R[(size_t)row * 1024 + tid * 4];
    float vv[4] = { v.x, v.y, v.z, v.w };
    float s  = vv[0] + vv[1] + vv[2] + vv[3];
    float s2 = vv[0]*vv[0] + vv[1]*vv[1] + vv[2]*vv[2] + vv[3]*vv[3];
#pragma unroll
    for (int o = 32; o > 0; o >>= 1) {
        s  += __shfl_down(s, o, 64);
        s2 += __shfl_down(s2, o, 64);
    }
    __shared__ float red[8];
    if ((tid & 63) == 0) { red[tid >> 6] = s; red[4 + (tid >> 6)] = s2; }
    __syncthreads();
    const float ts  = red[0] + red[1] + red[2] + red[3];
    const float ts2 = red[4] + red[5] + red[6] + red[7];
    const float mu  = ts * (1.0f / 1024.0f);
    const float var = ts2 * (1.0f / 1024.0f) - mu * mu;
    const float inv = rsqrtf(var + 1e-5f);
    ushort4 g4 = *(const ushort4*)&G[(size_t)row * 1024 + tid * 4];
    float4 gm = *(const float4*)&gamma[tid * 4];
    float4 bt = *(const float4*)&beta[tid * 4];
    USHORT gg[4]  = { g4.x, g4.y, g4.z, g4.w };
    float  gmm[4] = { gm.x, gm.y, gm.z, gm.w };
    float  btt[4] = { bt.x, bt.y, bt.z, bt.w };
    USHORT o4[4];
#pragma unroll
    for (int u = 0; u < 4; u++) {
        float nv = (vv[u] - mu) * inv * gmm[u] + btt[u];
        o4[u] = f2bf(nv * bf2f(gg[u]));
    }
    *(ushort4*)&NG[(size_t)row * 1024 + tid * 4] = make_ushort4(o4[0], o4[1], o4[2], o4[3]);
}

// ---------------------------------------------------------------------------
extern "C" void kernel_launch(void* const* d_in, const int* in_sizes, int n_in,
                              void* d_out, int out_size, void* d_ws, size_t ws_size,
                              hipStream_t stream) {
    const float* x     = (const float*)d_in[0];
    const float* Wq    = (const float*)d_in[1];
    const float* bq    = (const float*)d_in[2];
    const float* Wk    = (const float*)d_in[3];
    const float* bk    = (const float*)d_in[4];
    const float* Wv    = (const float*)d_in[5];
    const float* bv    = (const float*)d_in[6];
    const float* Wg    = (const float*)d_in[7];
    const float* bg    = (const float*)d_in[8];
    const float* Wo    = (const float*)d_in[9];
    const float* bo    = (const float*)d_in[10];
    const float* gamma = (const float*)d_in[11];
    const float* beta  = (const float*)d_in[12];

    // Workspace: 42 MB. x cast lives in d_out (dead before attn writes R there).
    char* ws = (char*)d_ws;
    const size_t MB = 1 << 20;
    USHORT* WqT = (USHORT*)(ws + 0 * MB);
    USHORT* WkT = (USHORT*)(ws + 2 * MB);
    USHORT* WvT = (USHORT*)(ws + 4 * MB);
    USHORT* WgT = (USHORT*)(ws + 6 * MB);
    USHORT* WoT = (USHORT*)(ws + 8 * MB);
    USHORT* Qb  = (USHORT*)(ws + 10 * MB);
    USHORT* Kb  = (USHORT*)(ws + 18 * MB);
    USHORT* VTb = (USHORT*)(ws + 26 * MB);
    USHORT* Gb  = (USHORT*)(ws + 34 * MB);
    USHORT* NGb = Qb;                 // Qb dead after attention
    USHORT* Xb  = (USHORT*)d_out;     // bf16 x (8 MB), dead after projections
    float*  Rf  = (float*)d_out;      // fp32 retained (16 MB), written by attn,
                                      // read by LN, overwritten by final GEMM

    k_cast_x<<<4096, 256, 0, stream>>>(x, Xb);
    {   // transpose+cast all 5 weights to bf16 [N,K]
        TWArgs ta;
        ta.src[0] = Wq; ta.src[1] = Wk; ta.src[2] = Wv; ta.src[3] = Wg; ta.src[4] = Wo;
        ta.dst[0] = WqT; ta.dst[1] = WkT; ta.dst[2] = WvT; ta.dst[3] = WgT; ta.dst[4] = WoT;
        k_transpose_w<<<dim3(16, 16, 5), 256, 0, stream>>>(ta);
    }
    {   // 4 fused projections: Q (scaled 1/8), K, V (transposed+decay-scaled), G (sigmoid)
        GArgs ga;
        ga.A = Xb;
        ga.W[0] = WqT; ga.W[1] = WkT; ga.W[2] = WvT; ga.W[3] = WgT;
        ga.bias[0] = bq; ga.bias[1] = bk; ga.bias[2] = bv; ga.bias[3] = bg;
        ga.dst[0] = Qb; ga.dst[1] = Kb; ga.dst[2] = nullptr; ga.dst[3] = Gb;
        ga.dstv = VTb;
        ga.scale[0] = 0.125f; ga.scale[1] = 1.0f; ga.scale[2] = 1.0f; ga.scale[3] = 1.0f;
        ga.mode[0] = 0; ga.mode[1] = 0; ga.mode[2] = 2; ga.mode[3] = 1;
        k_gemm<<<dim3(8, 32, 4), 256, 0, stream>>>(ga);
    }
    k_attn<<<dim3(32, 16), 256, 0, stream>>>(Qb, Kb, VTb, Rf);
    k_ln_gate<<<4096, 256, 0, stream>>>(Rf, Gb, gamma, beta, NGb);
    {   // output projection -> d_out as FP32 (mode 3), overwrites Rf
        GArgs go;
        go.A = NGb;
        for (int i = 0; i < 4; i++) {
            go.W[i] = WoT; go.bias[i] = bo; go.dst[i] = d_out;
            go.scale[i] = 1.0f; go.mode[i] = 3;
        }
        go.dstv = nullptr;
        k_gemm<<<dim3(8, 32, 1), 256, 0, stream>>>(go);
    }
}

// Round 9
// 225.932 us; speedup vs baseline: 1.3344x; 1.0340x over previous
//
#include <hip/hip_runtime.h>

typedef __attribute__((ext_vector_type(4))) float f32x4;
typedef __attribute__((ext_vector_type(8))) short bf16x8;
typedef unsigned short USHORT;

static __device__ __forceinline__ float bf2f(USHORT u) {
    return __uint_as_float(((unsigned)u) << 16);
}
static __device__ __forceinline__ USHORT f2bf(float f) {
    unsigned u = __float_as_uint(f);
    unsigned r = u + 0x7FFF + ((u >> 16) & 1);   // RTNE
    return (USHORT)(r >> 16);
}

// 16B/lane async global->LDS (m97). LDS dst must be wave-uniform base + lane*16.
#define GLDS16(gp, lp) __builtin_amdgcn_global_load_lds(                      \
    (const __attribute__((address_space(1))) unsigned int*)(gp),              \
    (__attribute__((address_space(3))) unsigned int*)(lp), 16, 0, 0)

// Barrier WITHOUT vmcnt drain (LDS ordering only) — keeps prefetch loads in flight.
#define LGKM_BARRIER() asm volatile("s_waitcnt lgkmcnt(0)\ns_barrier" ::: "memory")
// Barrier draining both (for glds double-buffer handoff).
#define FULL_BARRIER() asm volatile("s_waitcnt vmcnt(0) lgkmcnt(0)\ns_barrier" ::: "memory")

// ---------------------------------------------------------------------------
// Cast x fp32 [4096,1024] -> bf16 (into d_out scratch; dead before attn).
// ---------------------------------------------------------------------------
__global__ __launch_bounds__(256) void k_cast_x(const float* __restrict__ x,
                                                USHORT* __restrict__ xb) {
    const int i = (blockIdx.x * 256 + threadIdx.x) * 4;
    float4 v = *(const float4*)&x[i];
    *(ushort4*)&xb[i] = make_ushort4(f2bf(v.x), f2bf(v.y), f2bf(v.z), f2bf(v.w));
}

// ---------------------------------------------------------------------------
// Weight transpose + cast: W fp32 [K=1024, N=1024] -> WT bf16 [N,K], 5 mats
// ---------------------------------------------------------------------------
struct TWArgs { const float* src[5]; USHORT* dst[5]; };

__global__ __launch_bounds__(256) void k_transpose_w(TWArgs ta) {
    const float* __restrict__ W  = ta.src[blockIdx.z];
    USHORT* __restrict__      WT = ta.dst[blockIdx.z];
    __shared__ USHORT t[64][65];
    const int k0 = blockIdx.y * 64, n0 = blockIdx.x * 64;
    const int tid = threadIdx.x;
#pragma unroll
    for (int s = 0; s < 4; s++) {
        int slot = tid + s * 256;
        int row = slot >> 4, c4 = (slot & 15) * 4;      // row = k, c4 = n
        float4 vv = *(const float4*)&W[(size_t)(k0 + row) * 1024 + n0 + c4];
        t[row][c4 + 0] = f2bf(vv.x);
        t[row][c4 + 1] = f2bf(vv.y);
        t[row][c4 + 2] = f2bf(vv.z);
        t[row][c4 + 3] = f2bf(vv.w);
    }
    __syncthreads();
#pragma unroll
    for (int s = 0; s < 2; s++) {
        int slot = tid + s * 256;
        int n = slot >> 3, c8 = (slot & 7) * 8;         // n = row of WT, c8 = k
        USHORT tmp[8];
#pragma unroll
        for (int u = 0; u < 8; u++) tmp[u] = t[c8 + u][n];
        *(int4*)&WT[(size_t)(n0 + n) * 1024 + k0 + c8] = *(int4*)tmp;
    }
}

// ---------------------------------------------------------------------------
// GEMM: C[M,1024] = act(A[M,1024] @ W + bias) * scale, A bf16, W = WT[N,K] bf16.
// 128x128 tile, BK=32, 4 waves (2x2), 16x16x32 MFMA.
// Software pipeline: glds prefetch of tile k+1 into alternate LDS buffer while
// computing tile k; single manual barrier per iter (vmcnt drained one iter late).
// mode 0: bf16 store; mode 1: sigmoid bf16; mode 2: V transposed+decay-scaled
// as VT[b,h,d,s]; mode 3: fp32 store (final output).
// ---------------------------------------------------------------------------
struct GArgs {
    const USHORT* A;
    const USHORT* W[4];
    const float*  bias[4];
    void*         dst[4];
    USHORT*       dstv;       // VT output for mode 2
    float         scale[4];
    int           mode[4];
};

__global__ __launch_bounds__(256, 2) void k_gemm(GArgs ga) {
    const int z = blockIdx.z;
    const USHORT* __restrict__ A  = ga.A;
    const USHORT* __restrict__ BT = ga.W[z];
    __shared__ USHORT As[2][128 * 32];
    __shared__ USHORT Bs[2][128 * 32];
    const int tid = threadIdx.x;
    const int m0 = blockIdx.y * 128, n0 = blockIdx.x * 128;
    const int w = tid >> 6, l = tid & 63, lr = l & 15, q = l >> 4;
    const int wr = w >> 1, wc = w & 1;
    const int srow = tid >> 2, sco = (tid & 3) * 8;     // LDS byte addr = tid*16
    f32x4 acc[4][4] = {};
    // prefetch k-tile 0 into buffer 0
    GLDS16(&A [(size_t)(m0 + srow)      * 1024 + sco], &As[0][srow * 32 + sco]);
    GLDS16(&A [(size_t)(m0 + srow + 64) * 1024 + sco], &As[0][(srow + 64) * 32 + sco]);
    GLDS16(&BT[(size_t)(n0 + srow)      * 1024 + sco], &Bs[0][srow * 32 + sco]);
    GLDS16(&BT[(size_t)(n0 + srow + 64) * 1024 + sco], &Bs[0][(srow + 64) * 32 + sco]);
    for (int kt = 0; kt < 32; kt++) {
        const int cur = kt & 1;
        FULL_BARRIER();                       // drains glds issued last iter
        if (kt + 1 < 32) {                    // prefetch k+1; in flight during compute
            const int k1 = (kt + 1) * 32;
            const int nxt = 1 - cur;
            GLDS16(&A [(size_t)(m0 + srow)      * 1024 + k1 + sco], &As[nxt][srow * 32 + sco]);
            GLDS16(&A [(size_t)(m0 + srow + 64) * 1024 + k1 + sco], &As[nxt][(srow + 64) * 32 + sco]);
            GLDS16(&BT[(size_t)(n0 + srow)      * 1024 + k1 + sco], &Bs[nxt][srow * 32 + sco]);
            GLDS16(&BT[(size_t)(n0 + srow + 64) * 1024 + k1 + sco], &Bs[nxt][(srow + 64) * 32 + sco]);
        }
        bf16x8 af[4], bfr[4];
#pragma unroll
        for (int mi = 0; mi < 4; mi++)
            af[mi] = *(const bf16x8*)&As[cur][(wr * 64 + mi * 16 + lr) * 32 + q * 8];
#pragma unroll
        for (int ni = 0; ni < 4; ni++)
            bfr[ni] = *(const bf16x8*)&Bs[cur][(wc * 64 + ni * 16 + lr) * 32 + q * 8];
#pragma unroll
        for (int mi = 0; mi < 4; mi++)
#pragma unroll
            for (int ni = 0; ni < 4; ni++)
                acc[mi][ni] = __builtin_amdgcn_mfma_f32_16x16x32_bf16(
                    af[mi], bfr[ni], acc[mi][ni], 0, 0, 0);
    }
    const float scale = ga.scale[z];
    const int mode = ga.mode[z];
    const float* __restrict__ bias = ga.bias[z];
#pragma unroll
    for (int ni = 0; ni < 4; ni++) {
        int col = n0 + wc * 64 + ni * 16 + lr;          // D col = lane&15 (B free)
        float bv = bias[col];
#pragma unroll
        for (int mi = 0; mi < 4; mi++) {
            int r0 = m0 + wr * 64 + mi * 16 + q * 4;    // D row = quad*4+reg (A free)
            float vr[4];
#pragma unroll
            for (int r = 0; r < 4; r++) {
                float v = acc[mi][ni][r] + bv;
                if (mode == 1) v = 1.0f / (1.0f + __expf(-v));
                vr[r] = v * scale;
            }
            if (mode == 3) {
                float* df = (float*)ga.dst[z];
#pragma unroll
                for (int r = 0; r < 4; r++)
                    df[(size_t)(r0 + r) * 1024 + col] = vr[r];
            } else if (mode == 2) {
                // V[b,s,h*64+d] -> VT[((b*16+h)*64+d)*2048 + s], 4 consecutive s
                // scaled by 0.99^{-(s & 63)} (column decay factor)
                int b = r0 >> 11, s = r0 & 2047;
                int h = col >> 6, d = col & 63;
                const float NP1 = 1.0101010101010102f;          // 0.99^-1
                float c0 = exp2f(0.014499569695115089f * (float)(s & 63));
                float c1 = c0 * NP1, c2 = c1 * NP1, c3 = c2 * NP1;
                *(ushort4*)&ga.dstv[(size_t)(((b * 16 + h) * 64) + d) * 2048 + s] =
                    make_ushort4(f2bf(vr[0] * c0), f2bf(vr[1] * c1),
                                 f2bf(vr[2] * c2), f2bf(vr[3] * c3));
            } else {
                USHORT* db = (USHORT*)ga.dst[z];
#pragma unroll
                for (int r = 0; r < 4; r++)
                    db[(size_t)(r0 + r) * 1024 + col] = f2bf(vr[r]);
            }
        }
    }
}

// ---------------------------------------------------------------------------
// Attention v4: register-prefetch pipeline + LDS dbuf + single lgkm-only
// barrier per j-iter (global latency hidden behind compute). Padded LDS
// (stride 72), folded decay, v_perm P-pack, balanced pairing, no atomics.
// ---------------------------------------------------------------------------
__global__ __launch_bounds__(256, 2) void k_attn(const USHORT* __restrict__ Q,
                                                 const USHORT* __restrict__ K,
                                                 const USHORT* __restrict__ VT,
                                                 float* __restrict__ R) {
    const int bh = blockIdx.x;
    const int b = bh >> 4, h = bh & 15;
    const int rr = blockIdx.y;
    const int iblk = (rr < 8) ? rr : 23 - rr;   // co-resident pairs sum constant
    const int i0 = iblk * 128;
    const int tid = threadIdx.x, w = tid >> 6, l = tid & 63, lr = l & 15, q = l >> 4;
    __shared__ USHORT Qs[128 * 72];
    __shared__ USHORT Ks[2][64 * 72];
    __shared__ USHORT Vs[2][64 * 72];
    __shared__ USHORT Ps[4][32 * 72];
    const float L2D = -0.014499569695115089f;   // log2(0.99)
    const float C16 = 0.8514577710948755f;      // 0.99^16
    // stage Q tile [128 i][64 d] -> padded
#pragma unroll
    for (int s = 0; s < 4; s++) {
        int slot = tid + s * 256;
        int rw = slot >> 3, c8 = (slot & 7) * 8;
        *(int4*)&Qs[rw * 72 + c8] =
            *(const int4*)&Q[(size_t)(b * 2048 + i0 + rw) * 1024 + h * 64 + c8];
    }
    const int iw0 = i0 + w * 32;
    const int r0_ = tid >> 3, c0 = (tid & 7) * 8;      // rows r0_ and r0_+32
    const int njb = 2 * iblk + 2;
    int4 kv0, kv1, vv0, vv1;
    // prefetch j-tile 0 and commit to buffer 0
    kv0 = *(const int4*)&K [(size_t)(b * 2048 + r0_)      * 1024 + h * 64 + c0];
    kv1 = *(const int4*)&K [(size_t)(b * 2048 + r0_ + 32) * 1024 + h * 64 + c0];
    vv0 = *(const int4*)&VT[(size_t)(bh * 64 + r0_)      * 2048 + c0];
    vv1 = *(const int4*)&VT[(size_t)(bh * 64 + r0_ + 32) * 2048 + c0];
    *(int4*)&Ks[0][r0_ * 72 + c0]        = kv0;
    *(int4*)&Ks[0][(r0_ + 32) * 72 + c0] = kv1;
    *(int4*)&Vs[0][r0_ * 72 + c0]        = vv0;
    *(int4*)&Vs[0][(r0_ + 32) * 72 + c0] = vv1;
    f32x4 accr[4][2] = {};
    for (int jb = 0; jb < njb; jb++) {
        const int j0 = jb * 64;
        const int cur = jb & 1;
        if (jb + 1 < njb) {     // prefetch j+1 into regs; latency spans compute
            const int j1 = j0 + 64;
            kv0 = *(const int4*)&K [(size_t)(b * 2048 + j1 + r0_)      * 1024 + h * 64 + c0];
            kv1 = *(const int4*)&K [(size_t)(b * 2048 + j1 + r0_ + 32) * 1024 + h * 64 + c0];
            vv0 = *(const int4*)&VT[(size_t)(bh * 64 + r0_)      * 2048 + j1 + c0];
            vv1 = *(const int4*)&VT[(size_t)(bh * 64 + r0_ + 32) * 2048 + j1 + c0];
        }
        LGKM_BARRIER();          // prev-iter LDS writes visible; no vmcnt drain
        if (j0 <= iw0 + 31) {
            // Pt[64j x 32i] = K Q^T : D row=j (quad*4+reg), col=i (lane&15)
            f32x4 accp[4][2] = {};
#pragma unroll
            for (int kk = 0; kk < 2; kk++) {
                bf16x8 bqf[2];
#pragma unroll
                for (int it = 0; it < 2; it++)
                    bqf[it] = *(const bf16x8*)&Qs[(w * 32 + it * 16 + lr) * 72 + kk * 32 + q * 8];
#pragma unroll
                for (int jt = 0; jt < 4; jt++) {
                    bf16x8 akf = *(const bf16x8*)&Ks[cur][(jt * 16 + lr) * 72 + kk * 32 + q * 8];
#pragma unroll
                    for (int it = 0; it < 2; it++)
                        accp[jt][it] = __builtin_amdgcn_mfma_f32_16x16x32_bf16(
                            akf, bqf[it], accp[jt][it], 0, 0, 0);
                }
            }
            // row decay: one exp2f per tile; column decay already in Vs.
            const float fb = exp2f(L2D * (float)(iw0 - j0 + lr));
            const float F[2] = { fb, fb * C16 };
            const bool partial = (j0 + 63 > iw0);
#pragma unroll
            for (int jt = 0; jt < 4; jt++) {
#pragma unroll
                for (int it = 0; it < 2; it++) {
                    float v0 = accp[jt][it][0] * F[it];
                    float v1 = accp[jt][it][1] * F[it];
                    float v2 = accp[jt][it][2] * F[it];
                    float v3 = accp[jt][it][3] * F[it];
                    if (partial) {
                        const int ii = iw0 + it * 16 + lr;
                        const int jj = j0 + jt * 16 + q * 4;
                        if (jj + 0 > ii) v0 = 0.0f;
                        if (jj + 1 > ii) v1 = 0.0f;
                        if (jj + 2 > ii) v2 = 0.0f;
                        if (jj + 3 > ii) v3 = 0.0f;
                    }
                    // truncation-pack hi16 pairs (uniform scale bias cancels in LN)
                    unsigned w0 = __builtin_amdgcn_perm(
                        __float_as_uint(v1), __float_as_uint(v0), 0x07060302u);
                    unsigned w1 = __builtin_amdgcn_perm(
                        __float_as_uint(v3), __float_as_uint(v2), 0x07060302u);
                    *(uint2*)&Ps[w][(it * 16 + lr) * 72 + jt * 16 + q * 4] =
                        make_uint2(w0, w1);
                }
            }
            // within-wave LDS RAW fence (Ps write -> Ps read)
            asm volatile("s_waitcnt lgkmcnt(0)" ::: "memory");
            // retained^T[64d x 32i] += Vs * Pt
#pragma unroll
            for (int kk = 0; kk < 2; kk++) {
                bf16x8 bpf[2];
#pragma unroll
                for (int it = 0; it < 2; it++)
                    bpf[it] = *(const bf16x8*)&Ps[w][(it * 16 + lr) * 72 + kk * 32 + q * 8];
#pragma unroll
                for (int dt = 0; dt < 4; dt++) {
                    bf16x8 avf = *(const bf16x8*)&Vs[cur][(dt * 16 + lr) * 72 + kk * 32 + q * 8];
#pragma unroll
                    for (int it = 0; it < 2; it++)
                        accr[dt][it] = __builtin_amdgcn_mfma_f32_16x16x32_bf16(
                            avf, bpf[it], accr[dt][it], 0, 0, 0);
                }
            }
        }
        if (jb + 1 < njb) {      // commit prefetched tile to alternate buffer
            const int nxt = 1 - cur;
            *(int4*)&Ks[nxt][r0_ * 72 + c0]        = kv0;
            *(int4*)&Ks[nxt][(r0_ + 32) * 72 + c0] = kv1;
            *(int4*)&Vs[nxt][r0_ * 72 + c0]        = vv0;
            *(int4*)&Vs[nxt][(r0_ + 32) * 72 + c0] = vv1;
        }
    }
    // plain fp32 stores: lane's 4 regs = 4 consecutive d -> float4
#pragma unroll
    for (int it = 0; it < 2; it++) {
        int i = i0 + w * 32 + it * 16 + lr;
#pragma unroll
        for (int dt = 0; dt < 4; dt++) {
            *(f32x4*)&R[(size_t)(b * 2048 + i) * 1024 + h * 64 + dt * 16 + q * 4] =
                accr[dt][it];
        }
    }
}

// ---------------------------------------------------------------------------
// LayerNorm over D=1024 (R fp32) + gate multiply. One block per row.
// ---------------------------------------------------------------------------
__global__ __launch_bounds__(256) void k_ln_gate(const float* __restrict__ R,
                                                 const USHORT* __restrict__ G,
                                                 const float* __restrict__ gamma,
                                                 const float* __restrict__ beta,
                                                 USHORT* __restrict__ NG) {
    const int row = blockIdx.x, tid = threadIdx.x;
    const float4 v = *(const float4*)&R[(size_t)row * 1024 + tid * 4];
    float vv[4] = { v.x, v.y, v.z, v.w };
    float s  = vv[0] + vv[1] + vv[2] + vv[3];
    float s2 = vv[0]*vv[0] + vv[1]*vv[1] + vv[2]*vv[2] + vv[3]*vv[3];
#pragma unroll
    for (int o = 32; o > 0; o >>= 1) {
        s  += __shfl_down(s, o, 64);
        s2 += __shfl_down(s2, o, 64);
    }
    __shared__ float red[8];
    if ((tid & 63) == 0) { red[tid >> 6] = s; red[4 + (tid >> 6)] = s2; }
    __syncthreads();
    const float ts  = red[0] + red[1] + red[2] + red[3];
    const float ts2 = red[4] + red[5] + red[6] + red[7];
    const float mu  = ts * (1.0f / 1024.0f);
    const float var = ts2 * (1.0f / 1024.0f) - mu * mu;
    const float inv = rsqrtf(var + 1e-5f);
    ushort4 g4 = *(const ushort4*)&G[(size_t)row * 1024 + tid * 4];
    float4 gm = *(const float4*)&gamma[tid * 4];
    float4 bt = *(const float4*)&beta[tid * 4];
    USHORT gg[4]  = { g4.x, g4.y, g4.z, g4.w };
    float  gmm[4] = { gm.x, gm.y, gm.z, gm.w };
    float  btt[4] = { bt.x, bt.y, bt.z, bt.w };
    USHORT o4[4];
#pragma unroll
    for (int u = 0; u < 4; u++) {
        float nv = (vv[u] - mu) * inv * gmm[u] + btt[u];
        o4[u] = f2bf(nv * bf2f(gg[u]));
    }
    *(ushort4*)&NG[(size_t)row * 1024 + tid * 4] = make_ushort4(o4[0], o4[1], o4[2], o4[3]);
}

// ---------------------------------------------------------------------------
extern "C" void kernel_launch(void* const* d_in, const int* in_sizes, int n_in,
                              void* d_out, int out_size, void* d_ws, size_t ws_size,
                              hipStream_t stream) {
    const float* x     = (const float*)d_in[0];
    const float* Wq    = (const float*)d_in[1];
    const float* bq    = (const float*)d_in[2];
    const float* Wk    = (const float*)d_in[3];
    const float* bk    = (const float*)d_in[4];
    const float* Wv    = (const float*)d_in[5];
    const float* bv    = (const float*)d_in[6];
    const float* Wg    = (const float*)d_in[7];
    const float* bg    = (const float*)d_in[8];
    const float* Wo    = (const float*)d_in[9];
    const float* bo    = (const float*)d_in[10];
    const float* gamma = (const float*)d_in[11];
    const float* beta  = (const float*)d_in[12];

    // Workspace: 42 MB. x cast lives in d_out (dead before attn writes R there).
    char* ws = (char*)d_ws;
    const size_t MB = 1 << 20;
    USHORT* WqT = (USHORT*)(ws + 0 * MB);
    USHORT* WkT = (USHORT*)(ws + 2 * MB);
    USHORT* WvT = (USHORT*)(ws + 4 * MB);
    USHORT* WgT = (USHORT*)(ws + 6 * MB);
    USHORT* WoT = (USHORT*)(ws + 8 * MB);
    USHORT* Qb  = (USHORT*)(ws + 10 * MB);
    USHORT* Kb  = (USHORT*)(ws + 18 * MB);
    USHORT* VTb = (USHORT*)(ws + 26 * MB);
    USHORT* Gb  = (USHORT*)(ws + 34 * MB);
    USHORT* NGb = Qb;                 // Qb dead after attention
    USHORT* Xb  = (USHORT*)d_out;     // bf16 x (8 MB), dead after projections
    float*  Rf  = (float*)d_out;      // fp32 retained (16 MB), written by attn,
                                      // read by LN, overwritten by final GEMM

    k_cast_x<<<4096, 256, 0, stream>>>(x, Xb);
    {   // transpose+cast all 5 weights to bf16 [N,K]
        TWArgs ta;
        ta.src[0] = Wq; ta.src[1] = Wk; ta.src[2] = Wv; ta.src[3] = Wg; ta.src[4] = Wo;
        ta.dst[0] = WqT; ta.dst[1] = WkT; ta.dst[2] = WvT; ta.dst[3] = WgT; ta.dst[4] = WoT;
        k_transpose_w<<<dim3(16, 16, 5), 256, 0, stream>>>(ta);
    }
    {   // 4 fused projections: Q (scaled 1/8), K, V (transposed+decay-scaled), G (sigmoid)
        GArgs ga;
        ga.A = Xb;
        ga.W[0] = WqT; ga.W[1] = WkT; ga.W[2] = WvT; ga.W[3] = WgT;
        ga.bias[0] = bq; ga.bias[1] = bk; ga.bias[2] = bv; ga.bias[3] = bg;
        ga.dst[0] = Qb; ga.dst[1] = Kb; ga.dst[2] = nullptr; ga.dst[3] = Gb;
        ga.dstv = VTb;
        ga.scale[0] = 0.125f; ga.scale[1] = 1.0f; ga.scale[2] = 1.0f; ga.scale[3] = 1.0f;
        ga.mode[0] = 0; ga.mode[1] = 0; ga.mode[2] = 2; ga.mode[3] = 1;
        k_gemm<<<dim3(8, 32, 4), 256, 0, stream>>>(ga);
    }
    k_attn<<<dim3(32, 16), 256, 0, stream>>>(Qb, Kb, VTb, Rf);
    k_ln_gate<<<4096, 256, 0, stream>>>(Rf, Gb, gamma, beta, NGb);
    {   // output projection -> d_out as FP32 (mode 3), overwrites Rf
        GArgs go;
        go.A = NGb;
        for (int i = 0; i < 4; i++) {
            go.W[i] = WoT; go.bias[i] = bo; go.dst[i] = d_out;
            go.scale[i] = 1.0f; go.mode[i] = 3;
        }
        go.dstv = nullptr;
        k_gemm<<<dim3(8, 32, 1), 256, 0, stream>>>(go);
    }
}